// Round 13
// baseline (128.803 us; speedup 1.0000x reference)
//
#include <hip/hip_runtime.h>

// ---- problem constants ----
#define C_SZ   3
#define IMG_SZ 512
// per (c,g) GEMM: M = 64*32 = 2048, K = 256, N = 256
// Block: BM=128 x BN=256, 8 waves (2x4 grid of 64x64 wave tiles), 512 threads.
// 16 mtiles x 96 cg = 1536 blocks.

typedef short  short8 __attribute__((ext_vector_type(8)));   // 8 bf16 (4 VGPR)
typedef float  f32x4  __attribute__((ext_vector_type(4)));
typedef unsigned short u16;
typedef u16    u16x8  __attribute__((ext_vector_type(8)));

__device__ __forceinline__ u16 f2bf(float f) {
    unsigned u = __float_as_uint(f);
    u += 0x7FFFu + ((u >> 16) & 1u);          // round-to-nearest-even
    return (u16)(u >> 16);
}

__device__ __forceinline__ float tanh_fast(float v) {
    float e = __expf(2.f * v);
    return 1.f - 2.f * __builtin_amdgcn_rcpf(e + 1.f);
}

// async 16B global->LDS DMA. NOTE: global source is PER-LANE, LDS dest is
// wave-uniform base + lane*16 (m03/m104 semantics).
__device__ __forceinline__ void gload_lds16(const void* g, void* l) {
    __builtin_amdgcn_global_load_lds(
        (const __attribute__((address_space(1))) void*)g,
        (__attribute__((address_space(3))) void*)l, 16, 0, 0);
}

// ---------- prep: wt3[cg][kb][kg][n][e] = bf16(w[cg][kb*32+kg*8+e][n]) ----------
__global__ __launch_bounds__(256)
void prep_wt(const float* __restrict__ w, u16* __restrict__ wt) {
    const int cg = blockIdx.x;        // 0..95
    const int kb = blockIdx.y;        // 0..7
    __shared__ float T[32][260];      // +4 pad: conflict-free column gather
    const int tid = threadIdx.x;
    const float* wb = w + (size_t)cg * 65536 + (size_t)kb * 32 * 256;
    #pragma unroll
    for (int pass = 0; pass < 8; ++pass) {
        int q = pass * 256 + tid;
        int pl = q >> 6, o4 = (q & 63) * 4;
        float4 v = *reinterpret_cast<const float4*>(wb + (size_t)pl * 256 + o4);
        T[pl][o4 + 0] = v.x; T[pl][o4 + 1] = v.y;
        T[pl][o4 + 2] = v.z; T[pl][o4 + 3] = v.w;
    }
    __syncthreads();
    u16* dst = wt + ((size_t)cg * 8 + kb) * 8192;
    #pragma unroll
    for (int h0 = 0; h0 < 4; ++h0) {
        int h = h0 * 256 + tid;
        int kg = h >> 8, n = h & 255;
        u16x8 v;
        #pragma unroll
        for (int e = 0; e < 8; ++e) v[e] = f2bf(T[kg * 8 + e][n]);
        *reinterpret_cast<u16x8*>(dst + (size_t)kg * 2048 + n * 8) = v;
    }
}

// ---------- main GEMM: BM=128 x BN=256, 8 waves (each 64x64) ----------
// r12 structure with the B-staging source made PER-LANE (the r12 bug).
// B deduplicated through LDS: each phase's 16KB B slice staged once/block,
// ds_read by all 8 waves. 2-buffer rings for A and B; bottom barrier makes
// the 2-deep ring race-free; per-wave vmcnt(4) drains exactly stage t.
__global__ __launch_bounds__(512)
void obf_mfma(const float* __restrict__ x,
              const u16*  __restrict__ wt,
              const float* __restrict__ bias,
              const int*  __restrict__ perm,
              float* __restrict__ out)
{
    // bijective: 1536 = 8 xcd x 6 slots x 32 g  (g fastest within an XCD)
    const int bid  = blockIdx.x;
    const int xcd  = bid & 7;
    const int i    = bid >> 3;        // 0..191 within XCD
    const int g    = i & 31;          // cohort spans all 32 diagonals
    const int s    = xcd * 6 + (i >> 5);    // 0..47 = (c, mtile)
    const int c    = s >> 4;
    const int mtile = s & 15;         // 0..15 (M = 2048 / 128)
    const int cg   = c * 32 + g;

    const int tid  = threadIdx.x;
    const int lane = tid & 63, wv = tid >> 6;      // wv 0..7
    const int wr   = wv >> 2, wc = wv & 3;         // wave tile (row, col)
    const int r = lane & 15, kg = lane >> 4;

    __shared__ float As[2][4096];     // 2 x 16KB A ring (rows = 32 floats, 128B)
    __shared__ u16   Bs[2][8192];     // 2 x 16KB B ring (linear wt slice copy)

    int cp = 0;
    #pragma unroll
    for (int ii = 0; ii < C_SZ; ++ii) if (perm[ii] == c) cp = ii;

    // A staging: thread owns physical chunks q0 = wv*128+lane, q1 = q0+64 (1024 total).
    // chunk q -> row = q>>3, pos = q&7, logical k-chunk lpos = pos ^ (row&7).
    const float* g_src[2];
    #pragma unroll
    for (int j = 0; j < 2; ++j) {
        int q    = wv * 128 + j * 64 + lane;
        int row  = q >> 3;            // 0..127
        int lpos = (q & 7) ^ (row & 7);
        int mg   = mtile * 128 + row;
        int b    = mg >> 5, nh = mg & 31, nw = (g - nh) & 31;
        g_src[j] = x + (((size_t)(b * C_SZ + c) * IMG_SZ + nh * 16 + (lpos >> 2)) * IMG_SZ
                        + nw * 16 + (lpos & 3) * 4);
    }
    // B staging source: PER-LANE address (lane*8 u16 = 16B per lane).
    const u16* b_src = wt + (size_t)cg * 65536 + wv * 512 + lane * 8;

    // swizzled ds_read float offsets for A (involution of the source swizzle)
    const int p0 = (((2 * kg)     ^ (r & 7)) * 4);
    const int p1 = (((2 * kg + 1) ^ (r & 7)) * 4);
    const int rbase = (wr * 64 + r) * 32;          // wave row base (wr*64 % 8 == 0)

    f32x4 acc[4][4] = {};             // acc[mi][ni]: C^T fragment, reg axis = n

#define STAGE_A(t) do {                                                \
        float* d_ = &As[(t) & 1][0] + wv * 512;                        \
        gload_lds16(g_src[0] + (size_t)(t) * 1024, d_);                \
        gload_lds16(g_src[1] + (size_t)(t) * 1024, d_ + 256);          \
    } while (0)
// B slice for phase t: 8192 u16 contiguous; wave wv stages [wv*512, +512) and
// [wv*512+4096, +512) via two DMA (lane term already in b_src).
#define STAGE_B(t) do {                                                \
        u16* bd_ = &Bs[(t) & 1][0] + wv * 512;                         \
        const u16* bs_ = b_src + (size_t)(t) * 8192;                   \
        gload_lds16(bs_,        bd_);                                  \
        gload_lds16(bs_ + 4096, bd_ + 4096);                           \
    } while (0)

    // ---- prologue: stage 0 in flight (4 DMA/wave) ----
    STAGE_A(0);
    STAGE_B(0);

    #pragma unroll
    for (int t = 0; t < 8; ++t) {
        if (t < 7) {
            STAGE_A(t + 1);                           // 2 DMA
            STAGE_B(t + 1);                           // 2 DMA
            asm volatile("s_waitcnt vmcnt(4)" ::: "memory");  // drain stage t only
        } else {
            asm volatile("s_waitcnt vmcnt(0)" ::: "memory");
        }
        __builtin_amdgcn_sched_barrier(0);
        __builtin_amdgcn_s_barrier();                 // stage t visible to all

        const float* lb  = &As[t & 1][0];
        const u16*   lbB = &Bs[t & 1][0];
        short8 bf[4];
        #pragma unroll
        for (int ni = 0; ni < 4; ++ni)
            bf[ni] = *reinterpret_cast<const short8*>(
                lbB + kg * 2048 + (wc * 64 + ni * 16 + r) * 8);

        #pragma unroll
        for (int mi = 0; mi < 4; ++mi) {
            f32x4 v0 = *reinterpret_cast<const f32x4*>(lb + (rbase + mi * 16 * 32) + p0);
            f32x4 v1 = *reinterpret_cast<const f32x4*>(lb + (rbase + mi * 16 * 32) + p1);
            short8 af;
            af[0] = (short)f2bf(v0[0]); af[1] = (short)f2bf(v0[1]);
            af[2] = (short)f2bf(v0[2]); af[3] = (short)f2bf(v0[3]);
            af[4] = (short)f2bf(v1[0]); af[5] = (short)f2bf(v1[1]);
            af[6] = (short)f2bf(v1[2]); af[7] = (short)f2bf(v1[3]);
            #pragma unroll
            for (int ni = 0; ni < 4; ++ni)
                acc[mi][ni] = __builtin_amdgcn_mfma_f32_16x16x32_bf16(
                    bf[ni], af, acc[mi][ni], 0, 0, 0);   // swapped -> C^T
        }
        if (t < 7) __builtin_amdgcn_s_barrier();      // ring-2 safety (bottom)
    }
#undef STAGE_A
#undef STAGE_B

    // ---- epilogue: bias + tanh + un-patch + channel permute (float4 stores) ----
    // acc[mi][ni][reg]: m = mtile*128 + wr*64 + mi*16 + r
    //                   o = wc*64 + ni*16 + kg*4 + reg  (4 consecutive cols)
    const float* bb = bias + (size_t)cg * 256 + wc * 64 + kg * 4;
    float4 bsv[4];
    #pragma unroll
    for (int ni = 0; ni < 4; ++ni)
        bsv[ni] = *reinterpret_cast<const float4*>(bb + ni * 16);

    #pragma unroll
    for (int mi = 0; mi < 4; ++mi) {
        const int mg = mtile * 128 + wr * 64 + mi * 16 + r;
        const int b  = mg >> 5, nh = mg & 31, nw = (g - nh) & 31;
        float* pbase = out + ((size_t)(b * C_SZ + cp) * IMG_SZ + nh * 16) * IMG_SZ
                           + nw * 16 + kg * 4;
        #pragma unroll
        for (int ni = 0; ni < 4; ++ni) {
            const int rp = wc * 4 + ni;              // patch-local row
            float4 v;
            v.x = tanh_fast(acc[mi][ni][0] + bsv[ni].x);
            v.y = tanh_fast(acc[mi][ni][1] + bsv[ni].y);
            v.z = tanh_fast(acc[mi][ni][2] + bsv[ni].z);
            v.w = tanh_fast(acc[mi][ni][3] + bsv[ni].w);
            *reinterpret_cast<float4*>(pbase + (size_t)rp * IMG_SZ) = v;
        }
    }
}

extern "C" void kernel_launch(void* const* d_in, const int* in_sizes, int n_in,
                              void* d_out, int out_size, void* d_ws, size_t ws_size,
                              hipStream_t stream) {
    const float* x    = (const float*)d_in[0];
    const float* w    = (const float*)d_in[1];
    const float* bias = (const float*)d_in[2];
    const int*   perm = (const int*)d_in[3];
    float* out = (float*)d_out;
    u16*   wt  = (u16*)d_ws;          // 96*65536*2 = 12.6 MB scratch

    dim3 pgrid(C_SZ * 32, 8, 1);      // (96,8)
    prep_wt<<<pgrid, 256, 0, stream>>>(w, wt);

    obf_mfma<<<1536, 512, 0, stream>>>(x, wt, bias, perm, out);
}